// Round 1
// baseline (1320.509 us; speedup 1.0000x reference)
//
#include <hip/hip_runtime.h>
#include <hip/hip_bf16.h>
#include <cmath>

// ---------------------------------------------------------------------------
// GAT 2-layer forward, fp32.
// Pipeline:
//   1. k_gemm1   : h1 = x @ W1                      [N,256]
//   2. k_scores1 : s1src/s1dst per (node, head)     [N,8]
//   3. CSR build : histogram -> scan -> scatter (counting sort of edges by dst)
//   4. k_agg1    : per-dst online-softmax aggregation + bias + relu -> out1 [N,256]
//   5. k_gemm2   : h2 = out1 @ W2                   [N,40]
//   6. k_scores2 : s2src/s2dst per node             [N]
//   7. k_agg2    : per-dst online-softmax aggregation + bias -> out2 [N,40]
//   8. k_lsm     : log_softmax over 40 classes -> d_out
// ---------------------------------------------------------------------------

#define LEAKY(e) ((e) >= 0.f ? (e) : 0.2f * (e))

// ---------------- GEMM1: [M,128] @ [128,256] -> [M,256] --------------------
__global__ __launch_bounds__(256) void k_gemm1(const float* __restrict__ A,
                                               const float* __restrict__ B,
                                               float* __restrict__ C,
                                               int M, int K, int N) {
    __shared__ float As[64][17];   // 64 x 16 (+1 pad)
    __shared__ float Bs[16][65];   // 16 x 64 (+1 pad)
    int tid = threadIdx.x;
    int tx = tid & 15, ty = tid >> 4;
    int row0 = blockIdx.y * 64;
    int col0 = blockIdx.x * 64;
    float acc[4][4] = {};
    for (int k0 = 0; k0 < K; k0 += 16) {
        {   // A tile: 64 rows x 16 k
            int r = tid >> 2, kk = (tid & 3) * 4;
            int gr = row0 + r;
            float4 v = make_float4(0.f, 0.f, 0.f, 0.f);
            if (gr < M) v = *(const float4*)(A + (size_t)gr * K + k0 + kk);
            As[r][kk] = v.x; As[r][kk + 1] = v.y; As[r][kk + 2] = v.z; As[r][kk + 3] = v.w;
        }
        {   // B tile: 16 k x 64 cols
            int r = tid >> 4, cc = (tid & 15) * 4;
            float4 v = *(const float4*)(B + (size_t)(k0 + r) * N + col0 + cc);
            Bs[r][cc] = v.x; Bs[r][cc + 1] = v.y; Bs[r][cc + 2] = v.z; Bs[r][cc + 3] = v.w;
        }
        __syncthreads();
        #pragma unroll
        for (int kk = 0; kk < 16; ++kk) {
            float a[4], b[4];
            #pragma unroll
            for (int i = 0; i < 4; ++i) a[i] = As[ty * 4 + i][kk];
            #pragma unroll
            for (int j = 0; j < 4; ++j) b[j] = Bs[kk][tx * 4 + j];
            #pragma unroll
            for (int i = 0; i < 4; ++i)
                #pragma unroll
                for (int j = 0; j < 4; ++j) acc[i][j] += a[i] * b[j];
        }
        __syncthreads();
    }
    #pragma unroll
    for (int i = 0; i < 4; ++i) {
        int r = row0 + ty * 4 + i;
        if (r >= M) break;
        #pragma unroll
        for (int j = 0; j < 4; ++j)
            C[(size_t)r * N + col0 + tx * 4 + j] = acc[i][j];
    }
}

// ---------------- scores layer 1: per (n, head) 32-dot ---------------------
__global__ __launch_bounds__(256) void k_scores1(const float* __restrict__ h1,
                                                 const float* __restrict__ a_s,
                                                 const float* __restrict__ a_d,
                                                 float* __restrict__ ss,
                                                 float* __restrict__ sd, int NH) {
    int t = blockIdx.x * blockDim.x + threadIdx.x;
    if (t >= NH) return;
    int h = t & 7;
    const float* row = h1 + (size_t)t * 32;    // h1[(n*8+h)*32] == h1[n*256 + h*32]
    const float* as = a_s + h * 32;
    const float* ad = a_d + h * 32;
    float s1 = 0.f, s2 = 0.f;
    #pragma unroll
    for (int c = 0; c < 32; ++c) {
        float v = row[c];
        s1 += v * as[c];
        s2 += v * ad[c];
    }
    ss[t] = s1;
    sd[t] = s2;
}

// ---------------- CSR build ------------------------------------------------
__global__ __launch_bounds__(256) void k_deg(const int* __restrict__ ei, int E, int N,
                                             int* __restrict__ deg) {
    int e = blockIdx.x * blockDim.x + threadIdx.x;
    int total = E + N;
    if (e >= total) return;
    int dst = (e < E) ? ei[E + e] : (e - E);
    atomicAdd(&deg[dst], 1);
}

__global__ __launch_bounds__(1024) void k_scan(const int* __restrict__ deg,
                                               int* __restrict__ rowptr,
                                               int* __restrict__ cursor, int n) {
    __shared__ int buf[1024];
    __shared__ int carry_s;
    int tid = threadIdx.x;
    if (tid == 0) { carry_s = 0; rowptr[0] = 0; }
    __syncthreads();
    for (int base = 0; base < n; base += 1024) {
        int i = base + tid;
        int v = (i < n) ? deg[i] : 0;
        buf[tid] = v;
        __syncthreads();
        #pragma unroll
        for (int off = 1; off < 1024; off <<= 1) {
            int t = (tid >= off) ? buf[tid - off] : 0;
            __syncthreads();
            buf[tid] += t;
            __syncthreads();
        }
        int incl = buf[tid];
        int carry = carry_s;
        if (i < n) {
            rowptr[i + 1] = carry + incl;
            cursor[i] = carry + incl - v;   // exclusive prefix
        }
        __syncthreads();
        if (tid == 1023) carry_s = carry + incl;
        __syncthreads();
    }
}

__global__ __launch_bounds__(256) void k_scatter(const int* __restrict__ ei, int E, int N,
                                                 int* __restrict__ cursor,
                                                 int* __restrict__ csr_src) {
    int e = blockIdx.x * blockDim.x + threadIdx.x;
    int total = E + N;
    if (e >= total) return;
    int src, dst;
    if (e < E) { src = ei[e]; dst = ei[E + e]; }
    else       { src = dst = e - E; }
    int pos = atomicAdd(&cursor[dst], 1);
    csr_src[pos] = src;
}

// ---------------- layer-1 aggregation: block(256) per dst node -------------
__global__ __launch_bounds__(256) void k_agg1(const float* __restrict__ h1,
                                              const float* __restrict__ ssrc,
                                              const float* __restrict__ sdst,
                                              const int* __restrict__ rowptr,
                                              const int* __restrict__ csr_src,
                                              const float* __restrict__ b1,
                                              float* __restrict__ out1, int N) {
    int n = blockIdx.x;
    int tid = threadIdx.x;           // (head = tid>>5, c = tid&31)
    int head = tid >> 5;
    int beg = rowptr[n], end = rowptr[n + 1];
    float sd = sdst[n * 8 + head];
    float m = -INFINITY, l = 0.f, acc = 0.f;
    int src_n = 0; float ss_n = 0.f, hv_n = 0.f;
    if (beg < end) {
        src_n = csr_src[beg];
        ss_n = ssrc[src_n * 8 + head];
        hv_n = h1[(size_t)src_n * 256 + tid];
    }
    for (int idx = beg; idx < end; ++idx) {
        float ssv = ss_n, hv = hv_n;
        if (idx + 1 < end) {                    // prefetch next edge
            src_n = csr_src[idx + 1];
            ss_n = ssrc[src_n * 8 + head];
            hv_n = h1[(size_t)src_n * 256 + tid];
        }
        float e = LEAKY(ssv + sd);
        float nm = fmaxf(m, e);
        float scale = __expf(m - nm);           // 0 on first iter (m = -inf)
        float w = __expf(e - nm);
        l = l * scale + w;
        acc = acc * scale + w * hv;
        m = nm;
    }
    float o = acc / l + b1[tid];
    out1[(size_t)n * 256 + tid] = fmaxf(o, 0.f);   // relu fused (feeds layer 2)
}

// ---------------- GEMM2: [M,256] @ [256,40] -> [M,40] ----------------------
__global__ __launch_bounds__(256) void k_gemm2(const float* __restrict__ X,
                                               const float* __restrict__ W,
                                               float* __restrict__ Y, int M) {
    __shared__ float Xs[32][65];   // 32 nodes x 64 k (+1 pad)
    __shared__ float Ws[64][41];   // 64 k x 40 ch (+1 pad)
    int tid = threadIdx.x;
    int nl = tid >> 3;             // local node 0..31
    int cg = tid & 7;              // channel group (5 ch each)
    int n0 = blockIdx.x * 32;
    float acc[5] = {};
    for (int kt = 0; kt < 256; kt += 64) {
        #pragma unroll
        for (int i = 0; i < 2; ++i) {          // X tile: 2048 floats
            int q = tid + i * 256;
            int r = q >> 4, kk = (q & 15) * 4;
            int gr = n0 + r;
            float4 v = make_float4(0.f, 0.f, 0.f, 0.f);
            if (gr < M) v = *(const float4*)(X + (size_t)gr * 256 + kt + kk);
            Xs[r][kk] = v.x; Xs[r][kk + 1] = v.y; Xs[r][kk + 2] = v.z; Xs[r][kk + 3] = v.w;
        }
        #pragma unroll
        for (int i = 0; i < 10; ++i) {         // W tile: 2560 floats
            int q = tid + i * 256;
            int r = q / 40, c = q % 40;
            Ws[r][c] = W[(size_t)(kt + r) * 40 + c];
        }
        __syncthreads();
        #pragma unroll
        for (int k = 0; k < 64; ++k) {
            float xv = Xs[nl][k];
            #pragma unroll
            for (int j = 0; j < 5; ++j) acc[j] += xv * Ws[k][cg * 5 + j];
        }
        __syncthreads();
    }
    int n = n0 + nl;
    if (n < M) {
        #pragma unroll
        for (int j = 0; j < 5; ++j) Y[(size_t)n * 40 + cg * 5 + j] = acc[j];
    }
}

// ---------------- scores layer 2: per node 40-dot --------------------------
__global__ __launch_bounds__(256) void k_scores2(const float* __restrict__ h2,
                                                 const float* __restrict__ a2s,
                                                 const float* __restrict__ a2d,
                                                 float* __restrict__ ss,
                                                 float* __restrict__ sd, int N) {
    int n = blockIdx.x * blockDim.x + threadIdx.x;
    if (n >= N) return;
    const float* row = h2 + (size_t)n * 40;
    float s1 = 0.f, s2 = 0.f;
    #pragma unroll
    for (int c = 0; c < 40; ++c) {
        float v = row[c];
        s1 += v * a2s[c];
        s2 += v * a2d[c];
    }
    ss[n] = s1;
    sd[n] = s2;
}

// ---------------- layer-2 aggregation: wave(64) per dst node ---------------
__global__ __launch_bounds__(256) void k_agg2(const float* __restrict__ h2,
                                              const float* __restrict__ ss,
                                              const float* __restrict__ sd,
                                              const int* __restrict__ rowptr,
                                              const int* __restrict__ csr_src,
                                              const float* __restrict__ b2,
                                              float* __restrict__ out2, int N) {
    int lane = threadIdx.x & 63;
    int wid = threadIdx.x >> 6;
    int n = blockIdx.x * 4 + wid;
    if (n >= N) return;
    int beg = rowptr[n], end = rowptr[n + 1];
    float sdn = sd[n];
    float m = -INFINITY, l = 0.f, acc = 0.f;
    int src_n = 0; float ss_n = 0.f, hv_n = 0.f;
    if (beg < end) {
        src_n = csr_src[beg];
        ss_n = ss[src_n];
        hv_n = (lane < 40) ? h2[(size_t)src_n * 40 + lane] : 0.f;
    }
    for (int idx = beg; idx < end; ++idx) {
        float ssv = ss_n, hv = hv_n;
        if (idx + 1 < end) {
            src_n = csr_src[idx + 1];
            ss_n = ss[src_n];
            hv_n = (lane < 40) ? h2[(size_t)src_n * 40 + lane] : 0.f;
        }
        float e = LEAKY(ssv + sdn);
        float nm = fmaxf(m, e);
        float scale = __expf(m - nm);
        float w = __expf(e - nm);
        l = l * scale + w;
        acc = acc * scale + w * hv;
        m = nm;
    }
    if (lane < 40) out2[(size_t)n * 40 + lane] = acc / l + b2[lane];
}

// ---------------- log_softmax over 40 classes: wave per node ---------------
__global__ __launch_bounds__(256) void k_lsm(const float* __restrict__ out2,
                                             float* __restrict__ out, int N) {
    int lane = threadIdx.x & 63;
    int wid = threadIdx.x >> 6;
    int n = blockIdx.x * 4 + wid;
    if (n >= N) return;
    float v = (lane < 40) ? out2[(size_t)n * 40 + lane] : -INFINITY;
    float m = v;
    #pragma unroll
    for (int off = 32; off; off >>= 1) m = fmaxf(m, __shfl_xor(m, off, 64));
    float ex = (lane < 40) ? __expf(v - m) : 0.f;
    float s = ex;
    #pragma unroll
    for (int off = 32; off; off >>= 1) s += __shfl_xor(s, off, 64);
    if (lane < 40) out[(size_t)n * 40 + lane] = v - m - logf(s);
}

// ---------------------------------------------------------------------------
extern "C" void kernel_launch(void* const* d_in, const int* in_sizes, int n_in,
                              void* d_out, int out_size, void* d_ws, size_t ws_size,
                              hipStream_t stream) {
    const float* x   = (const float*)d_in[0];
    const int*   ei  = (const int*)d_in[1];
    const float* W1  = (const float*)d_in[2];
    const float* a1s = (const float*)d_in[3];
    const float* a1d = (const float*)d_in[4];
    const float* b1  = (const float*)d_in[5];
    const float* W2  = (const float*)d_in[6];
    const float* a2s = (const float*)d_in[7];
    const float* a2d = (const float*)d_in[8];
    const float* b2  = (const float*)d_in[9];
    float* out = (float*)d_out;

    const int N = in_sizes[0] / 128;   // 100000
    const int E = in_sizes[1] / 2;     // 1600000
    const int ET = E + N;              // with self loops

    // ---- workspace layout (floats) ----
    float* ws = (float*)d_ws;
    const size_t szH1 = (size_t)N * 256;
    float* f_h1   = ws;
    float* f_out1 = f_h1 + szH1;
    float* f_s1s  = f_out1 + szH1;
    float* f_s1d  = f_s1s + (size_t)N * 8;
    int*   i_deg  = (int*)(f_s1d + (size_t)N * 8);
    int*   i_row  = i_deg + N + 16;
    int*   i_cur  = i_row + N + 16;
    int*   i_csr  = i_cur + N + 16;
    // layer-2 buffers overlay h1 (h1 is dead after k_agg1)
    float* f_h2   = ws;                         // N*40
    float* f_out2 = ws + (size_t)N * 40;        // N*40
    float* f_s2s  = ws + (size_t)N * 80;        // N
    float* f_s2d  = f_s2s + N;                  // N

    // ---- CSR build (graph is the same for both layers) ----
    hipMemsetAsync(i_deg, 0, (size_t)N * sizeof(int), stream);
    k_deg<<<(ET + 255) / 256, 256, 0, stream>>>(ei, E, N, i_deg);
    k_scan<<<1, 1024, 0, stream>>>(i_deg, i_row, i_cur, N);
    k_scatter<<<(ET + 255) / 256, 256, 0, stream>>>(ei, E, N, i_cur, i_csr);

    // ---- layer 1 ----
    {
        dim3 grid(256 / 64, (N + 63) / 64);
        k_gemm1<<<grid, 256, 0, stream>>>(x, W1, f_h1, N, 128, 256);
    }
    k_scores1<<<(N * 8 + 255) / 256, 256, 0, stream>>>(f_h1, a1s, a1d, f_s1s, f_s1d, N * 8);
    k_agg1<<<N, 256, 0, stream>>>(f_h1, f_s1s, f_s1d, i_row, i_csr, b1, f_out1, N);

    // ---- layer 2 ----
    k_gemm2<<<(N + 31) / 32, 256, 0, stream>>>(f_out1, W2, f_h2, N);
    k_scores2<<<(N + 255) / 256, 256, 0, stream>>>(f_h2, a2s, a2d, f_s2s, f_s2d, N);
    k_agg2<<<(N + 3) / 4, 256, 0, stream>>>(f_h2, f_s2s, f_s2d, i_row, i_csr, b2, f_out2, N);

    // ---- log_softmax ----
    k_lsm<<<(N + 3) / 4, 256, 0, stream>>>(f_out2, out, N);
}

// Round 2
// 1009.758 us; speedup vs baseline: 1.3077x; 1.3077x over previous
//
#include <hip/hip_runtime.h>
#include <hip/hip_bf16.h>
#include <cmath>

// ---------------------------------------------------------------------------
// GAT 2-layer forward. Softmax weights precomputed per edge (k_wts*), value
// matrices stored bf16 to halve gather bytes. Aggregation = pure weighted sum.
// ---------------------------------------------------------------------------

#define LEAKY(e) ((e) >= 0.f ? (e) : 0.2f * (e))

typedef unsigned short ushortT;
typedef unsigned int uintT;

static __device__ __forceinline__ float bf2f(ushortT u) {
    return __uint_as_float(((uintT)u) << 16);
}
static __device__ __forceinline__ ushortT f2bf(float f) {
    __hip_bfloat16 h = __float2bfloat16(f);   // RNE
    return *reinterpret_cast<ushortT*>(&h);
}

// ---------------- GEMM1: [M,128] @ [128,256] -> bf16 [M,256] ---------------
__global__ __launch_bounds__(256) void k_gemm1(const float* __restrict__ A,
                                               const float* __restrict__ B,
                                               ushortT* __restrict__ C,
                                               int M, int K, int N) {
    __shared__ float As[64][17];
    __shared__ float Bs[16][65];
    int tid = threadIdx.x;
    int tx = tid & 15, ty = tid >> 4;
    int row0 = blockIdx.y * 64;
    int col0 = blockIdx.x * 64;
    float acc[4][4] = {};
    for (int k0 = 0; k0 < K; k0 += 16) {
        {
            int r = tid >> 2, kk = (tid & 3) * 4;
            int gr = row0 + r;
            float4 v = make_float4(0.f, 0.f, 0.f, 0.f);
            if (gr < M) v = *(const float4*)(A + (size_t)gr * K + k0 + kk);
            As[r][kk] = v.x; As[r][kk + 1] = v.y; As[r][kk + 2] = v.z; As[r][kk + 3] = v.w;
        }
        {
            int r = tid >> 4, cc = (tid & 15) * 4;
            float4 v = *(const float4*)(B + (size_t)(k0 + r) * N + col0 + cc);
            Bs[r][cc] = v.x; Bs[r][cc + 1] = v.y; Bs[r][cc + 2] = v.z; Bs[r][cc + 3] = v.w;
        }
        __syncthreads();
        #pragma unroll
        for (int kk = 0; kk < 16; ++kk) {
            float a[4], b[4];
            #pragma unroll
            for (int i = 0; i < 4; ++i) a[i] = As[ty * 4 + i][kk];
            #pragma unroll
            for (int j = 0; j < 4; ++j) b[j] = Bs[kk][tx * 4 + j];
            #pragma unroll
            for (int i = 0; i < 4; ++i)
                #pragma unroll
                for (int j = 0; j < 4; ++j) acc[i][j] += a[i] * b[j];
        }
        __syncthreads();
    }
    #pragma unroll
    for (int i = 0; i < 4; ++i) {
        int r = row0 + ty * 4 + i;
        if (r >= M) break;
        ushort4 u;
        u.x = f2bf(acc[i][0]); u.y = f2bf(acc[i][1]);
        u.z = f2bf(acc[i][2]); u.w = f2bf(acc[i][3]);
        *(ushort4*)(C + (size_t)r * N + col0 + tx * 4) = u;
    }
}

// ---------------- scores layer 1: per (n, head) 32-dot over bf16 -----------
__global__ __launch_bounds__(256) void k_scores1(const ushortT* __restrict__ h1,
                                                 const float* __restrict__ a_s,
                                                 const float* __restrict__ a_d,
                                                 float* __restrict__ ss,
                                                 float* __restrict__ sd, int NH) {
    int t = blockIdx.x * blockDim.x + threadIdx.x;
    if (t >= NH) return;
    int h = t & 7;
    const uint4* row = (const uint4*)(h1 + (size_t)t * 32);
    const float* as = a_s + h * 32;
    const float* ad = a_d + h * 32;
    float s1 = 0.f, s2 = 0.f;
    #pragma unroll
    for (int q = 0; q < 4; ++q) {
        uint4 u = row[q];
        uintT w[4] = {u.x, u.y, u.z, u.w};
        #pragma unroll
        for (int k = 0; k < 4; ++k) {
            float f0 = __uint_as_float(w[k] << 16);
            float f1 = __uint_as_float(w[k] & 0xffff0000u);
            int c = q * 8 + k * 2;
            s1 += f0 * as[c] + f1 * as[c + 1];
            s2 += f0 * ad[c] + f1 * ad[c + 1];
        }
    }
    ss[t] = s1;
    sd[t] = s2;
}

// ---------------- CSR build ------------------------------------------------
__global__ __launch_bounds__(256) void k_deg(const int* __restrict__ ei, int E, int N,
                                             int* __restrict__ deg) {
    int e = blockIdx.x * blockDim.x + threadIdx.x;
    int total = E + N;
    if (e >= total) return;
    int dst = (e < E) ? ei[E + e] : (e - E);
    atomicAdd(&deg[dst], 1);
}

__global__ __launch_bounds__(1024) void k_scan(const int* __restrict__ deg,
                                               int* __restrict__ rowptr,
                                               int* __restrict__ cursor, int n) {
    __shared__ int wsum[16];
    __shared__ int carry_s;
    int tid = threadIdx.x, lane = tid & 63, wid = tid >> 6;
    if (tid == 0) { carry_s = 0; rowptr[0] = 0; }
    __syncthreads();
    for (int base = 0; base < n; base += 1024) {
        int i = base + tid;
        int v = (i < n) ? deg[i] : 0;
        int incl = v;
        #pragma unroll
        for (int off = 1; off < 64; off <<= 1) {
            int t = __shfl_up(incl, off, 64);
            if (lane >= off) incl += t;
        }
        if (lane == 63) wsum[wid] = incl;
        __syncthreads();
        if (wid == 0) {
            int s = (lane < 16) ? wsum[lane] : 0;
            #pragma unroll
            for (int off = 1; off < 16; off <<= 1) {
                int t = __shfl_up(s, off, 64);
                if (lane >= off) s += t;
            }
            if (lane < 16) wsum[lane] = s;
        }
        __syncthreads();
        int waveoff = (wid > 0) ? wsum[wid - 1] : 0;
        int carry = carry_s;
        int gincl = carry + waveoff + incl;
        if (i < n) { rowptr[i + 1] = gincl; cursor[i] = gincl - v; }
        __syncthreads();
        if (tid == 0) carry_s = carry + wsum[15];
        __syncthreads();
    }
}

__global__ __launch_bounds__(256) void k_scatter(const int* __restrict__ ei, int E, int N,
                                                 int* __restrict__ cursor,
                                                 int* __restrict__ csr_src) {
    int e = blockIdx.x * blockDim.x + threadIdx.x;
    int total = E + N;
    if (e >= total) return;
    int src, dst;
    if (e < E) { src = ei[e]; dst = ei[E + e]; }
    else       { src = dst = e - E; }
    int pos = atomicAdd(&cursor[dst], 1);
    csr_src[pos] = src;
}

// ---------------- layer-1 weights: wave per dst, 8 edges x 8 heads ---------
__global__ __launch_bounds__(256) void k_wts1(const float* __restrict__ ssrc,
                                              const float* __restrict__ sdst,
                                              const int* __restrict__ rowptr,
                                              const int* __restrict__ csr_src,
                                              ushortT* __restrict__ pbuf,
                                              float* __restrict__ denom, int N) {
    int lane = threadIdx.x & 63;
    int wid = threadIdx.x >> 6;
    int n = blockIdx.x * 4 + wid;
    if (n >= N) return;
    int head = lane & 7, es = lane >> 3;
    int beg = rowptr[n], end = rowptr[n + 1];
    float sdn = sdst[(size_t)n * 8 + head];
    // pass 1: per-head max
    float m = -INFINITY;
    for (int i0 = beg; i0 < end; i0 += 8) {
        int i = i0 + es;
        float e = -INFINITY;
        if (i < end) {
            int s = csr_src[i];
            e = LEAKY(ssrc[(size_t)s * 8 + head] + sdn);
        }
        m = fmaxf(m, e);
    }
    m = fmaxf(m, __shfl_xor(m, 8, 64));
    m = fmaxf(m, __shfl_xor(m, 16, 64));
    m = fmaxf(m, __shfl_xor(m, 32, 64));
    // pass 2: p = exp(e-m), store bf16, accumulate denom from rounded value
    float l = 0.f;
    for (int i0 = beg; i0 < end; i0 += 8) {
        int i = i0 + es;
        if (i < end) {
            int s = csr_src[i];
            float e = LEAKY(ssrc[(size_t)s * 8 + head] + sdn);
            ushortT pb = f2bf(__expf(e - m));
            pbuf[(size_t)i * 8 + head] = pb;
            l += bf2f(pb);
        }
    }
    l += __shfl_xor(l, 8, 64);
    l += __shfl_xor(l, 16, 64);
    l += __shfl_xor(l, 32, 64);
    if (es == 0) denom[(size_t)n * 8 + head] = l;
}

// ---------------- layer-1 aggregation: wave per dst, 4 ch/lane -------------
__global__ __launch_bounds__(256) void k_agg1(const ushortT* __restrict__ h1,
                                              const ushortT* __restrict__ pbuf,
                                              const float* __restrict__ denom,
                                              const int* __restrict__ rowptr,
                                              const int* __restrict__ csr_src,
                                              const float* __restrict__ b1,
                                              float* __restrict__ out1, int N) {
    int lane = threadIdx.x & 63;
    int wid = threadIdx.x >> 6;
    int n = blockIdx.x * 4 + wid;
    if (n >= N) return;
    int head = lane >> 3;
    int beg = rowptr[n], end = rowptr[n + 1];
    float a0 = 0.f, a1 = 0.f, a2 = 0.f, a3 = 0.f;
    int src_n = 0; float p_n = 0.f;
    if (beg < end) {
        src_n = csr_src[beg];
        p_n = bf2f(pbuf[(size_t)beg * 8 + head]);
    }
    for (int idx = beg; idx < end; ++idx) {
        int src = src_n; float p = p_n;
        if (idx + 1 < end) {
            src_n = csr_src[idx + 1];
            p_n = bf2f(pbuf[(size_t)(idx + 1) * 8 + head]);
        }
        uint2 v = ((const uint2*)(h1 + (size_t)src * 256))[lane];
        float h0 = __uint_as_float(v.x << 16);
        float h1v = __uint_as_float(v.x & 0xffff0000u);
        float h2v = __uint_as_float(v.y << 16);
        float h3 = __uint_as_float(v.y & 0xffff0000u);
        a0 += p * h0; a1 += p * h1v; a2 += p * h2v; a3 += p * h3;
    }
    float inv = 1.f / denom[(size_t)n * 8 + head];
    const float4 bb = *(const float4*)(b1 + lane * 4);
    float4 o;
    o.x = fmaxf(a0 * inv + bb.x, 0.f);
    o.y = fmaxf(a1 * inv + bb.y, 0.f);
    o.z = fmaxf(a2 * inv + bb.z, 0.f);
    o.w = fmaxf(a3 * inv + bb.w, 0.f);
    *(float4*)(out1 + (size_t)n * 256 + lane * 4) = o;
}

// ---------------- GEMM2: [M,256] @ [256,40] -> bf16 h2 + fused scores ------
__global__ __launch_bounds__(256) void k_gemm2(const float* __restrict__ X,
                                               const float* __restrict__ W,
                                               const float* __restrict__ a2s,
                                               const float* __restrict__ a2d,
                                               ushortT* __restrict__ H2,
                                               float* __restrict__ s2s,
                                               float* __restrict__ s2d, int M) {
    __shared__ float Xs[32][65];
    __shared__ float Ws[64][41];
    __shared__ float red_s[32][8];
    __shared__ float red_d[32][8];
    int tid = threadIdx.x;
    int nl = tid >> 3;
    int cg = tid & 7;
    int n0 = blockIdx.x * 32;
    float acc[5] = {};
    for (int kt = 0; kt < 256; kt += 64) {
        #pragma unroll
        for (int i = 0; i < 2; ++i) {
            int q = tid + i * 256;
            int r = q >> 4, kk = (q & 15) * 4;
            int gr = n0 + r;
            float4 v = make_float4(0.f, 0.f, 0.f, 0.f);
            if (gr < M) v = *(const float4*)(X + (size_t)gr * 256 + kt + kk);
            Xs[r][kk] = v.x; Xs[r][kk + 1] = v.y; Xs[r][kk + 2] = v.z; Xs[r][kk + 3] = v.w;
        }
        #pragma unroll
        for (int i = 0; i < 10; ++i) {
            int q = tid + i * 256;
            int r = q / 40, c = q % 40;
            Ws[r][c] = W[(size_t)(kt + r) * 40 + c];
        }
        __syncthreads();
        #pragma unroll
        for (int k = 0; k < 64; ++k) {
            float xv = Xs[nl][k];
            #pragma unroll
            for (int j = 0; j < 5; ++j) acc[j] += xv * Ws[k][cg * 5 + j];
        }
        __syncthreads();
    }
    int n = n0 + nl;
    float ps = 0.f, pd = 0.f;
    #pragma unroll
    for (int j = 0; j < 5; ++j) {
        ps += acc[j] * a2s[cg * 5 + j];
        pd += acc[j] * a2d[cg * 5 + j];
    }
    red_s[nl][cg] = ps;
    red_d[nl][cg] = pd;
    if (n < M) {
        #pragma unroll
        for (int j = 0; j < 5; ++j) H2[(size_t)n * 40 + cg * 5 + j] = f2bf(acc[j]);
    }
    __syncthreads();
    if (cg == 0 && n < M) {
        float S = 0.f, D = 0.f;
        #pragma unroll
        for (int k = 0; k < 8; ++k) { S += red_s[nl][k]; D += red_d[nl][k]; }
        s2s[n] = S;
        s2d[n] = D;
    }
}

// ---------------- layer-2 weights: wave per dst, 64 edges/iter -------------
__global__ __launch_bounds__(256) void k_wts2(const float* __restrict__ ss,
                                              const float* __restrict__ sd,
                                              const int* __restrict__ rowptr,
                                              const int* __restrict__ csr_src,
                                              float* __restrict__ pbuf,
                                              float* __restrict__ denom, int N) {
    int lane = threadIdx.x & 63;
    int wid = threadIdx.x >> 6;
    int n = blockIdx.x * 4 + wid;
    if (n >= N) return;
    int beg = rowptr[n], end = rowptr[n + 1];
    float sdn = sd[n];
    float m = -INFINITY;
    for (int i0 = beg; i0 < end; i0 += 64) {
        int i = i0 + lane;
        float e = -INFINITY;
        if (i < end) e = LEAKY(ss[csr_src[i]] + sdn);
        m = fmaxf(m, e);
    }
    #pragma unroll
    for (int off = 1; off < 64; off <<= 1) m = fmaxf(m, __shfl_xor(m, off, 64));
    float l = 0.f;
    for (int i0 = beg; i0 < end; i0 += 64) {
        int i = i0 + lane;
        if (i < end) {
            float e = LEAKY(ss[csr_src[i]] + sdn);
            float p = __expf(e - m);
            pbuf[i] = p;
            l += p;
        }
    }
    #pragma unroll
    for (int off = 1; off < 64; off <<= 1) l += __shfl_xor(l, off, 64);
    if (lane == 0) denom[n] = l;
}

// ---------------- layer-2 aggregation: wave per dst ------------------------
__global__ __launch_bounds__(256) void k_agg2(const ushortT* __restrict__ h2,
                                              const float* __restrict__ pbuf,
                                              const float* __restrict__ denom,
                                              const int* __restrict__ rowptr,
                                              const int* __restrict__ csr_src,
                                              const float* __restrict__ b2,
                                              float* __restrict__ out2, int N) {
    int lane = threadIdx.x & 63;
    int wid = threadIdx.x >> 6;
    int n = blockIdx.x * 4 + wid;
    if (n >= N) return;
    int beg = rowptr[n], end = rowptr[n + 1];
    float acc = 0.f;
    int src_n = 0; float p_n = 0.f;
    if (beg < end) { src_n = csr_src[beg]; p_n = pbuf[beg]; }
    for (int idx = beg; idx < end; ++idx) {
        int src = src_n; float p = p_n;
        if (idx + 1 < end) { src_n = csr_src[idx + 1]; p_n = pbuf[idx + 1]; }
        float hv = (lane < 40) ? bf2f(h2[(size_t)src * 40 + lane]) : 0.f;
        acc += p * hv;
    }
    if (lane < 40) out2[(size_t)n * 40 + lane] = acc / denom[n] + b2[lane];
}

// ---------------- log_softmax over 40 classes: wave per node ---------------
__global__ __launch_bounds__(256) void k_lsm(const float* __restrict__ out2,
                                             float* __restrict__ out, int N) {
    int lane = threadIdx.x & 63;
    int wid = threadIdx.x >> 6;
    int n = blockIdx.x * 4 + wid;
    if (n >= N) return;
    float v = (lane < 40) ? out2[(size_t)n * 40 + lane] : -INFINITY;
    float m = v;
    #pragma unroll
    for (int off = 32; off; off >>= 1) m = fmaxf(m, __shfl_xor(m, off, 64));
    float ex = (lane < 40) ? __expf(v - m) : 0.f;
    float s = ex;
    #pragma unroll
    for (int off = 32; off; off >>= 1) s += __shfl_xor(s, off, 64);
    if (lane < 40) out[(size_t)n * 40 + lane] = v - m - logf(s);
}

// ---------------------------------------------------------------------------
extern "C" void kernel_launch(void* const* d_in, const int* in_sizes, int n_in,
                              void* d_out, int out_size, void* d_ws, size_t ws_size,
                              hipStream_t stream) {
    const float* x   = (const float*)d_in[0];
    const int*   ei  = (const int*)d_in[1];
    const float* W1  = (const float*)d_in[2];
    const float* a1s = (const float*)d_in[3];
    const float* a1d = (const float*)d_in[4];
    const float* b1  = (const float*)d_in[5];
    const float* W2  = (const float*)d_in[6];
    const float* a2s = (const float*)d_in[7];
    const float* a2d = (const float*)d_in[8];
    const float* b2  = (const float*)d_in[9];
    float* out = (float*)d_out;

    const int N = in_sizes[0] / 128;   // 100000
    const int E = in_sizes[1] / 2;     // 1600000
    const int ET = E + N;

    // ---- workspace layout (bytes) ----
    char* w = (char*)d_ws;
    ushortT* h1b = (ushortT*)w;                         // N*256 bf16 (51.2 MB)
    char* w1 = w + (size_t)N * 256 * 2;
    float* f_out1 = (float*)w1;                          // N*256 f32 (102.4 MB)
    char* w2 = w1 + (size_t)N * 256 * 4;
    float* f_s1s = (float*)w2;                           // N*8
    float* f_s1d = f_s1s + (size_t)N * 8;
    float* f_den1 = f_s1d + (size_t)N * 8;
    ushortT* p1b = (ushortT*)(f_den1 + (size_t)N * 8);   // ET*8 bf16 (27.2 MB)
    int* i_deg = (int*)(p1b + (size_t)ET * 8);
    int* i_row = i_deg + N + 16;
    int* i_cur = i_row + N + 16;
    int* i_csr = i_cur + N + 16;
    // layer-2 buffers overlay h1b (dead after k_agg1)
    ushortT* h2b  = (ushortT*)w;                         // N*40 bf16 (8 MB)
    float* f_out2 = (float*)(w + (size_t)N * 40 * 2);    // N*40 f32 (16 MB)
    float* f_s2s  = f_out2 + (size_t)N * 40;
    float* f_s2d  = f_s2s + N;
    float* f_den2 = f_s2d + N;
    float* p2     = f_den2 + N;                          // ET f32 (6.8 MB)

    const int nb4 = (N + 3) / 4;

    // ---- CSR build ----
    hipMemsetAsync(i_deg, 0, (size_t)N * sizeof(int), stream);
    k_deg<<<(ET + 255) / 256, 256, 0, stream>>>(ei, E, N, i_deg);
    k_scan<<<1, 1024, 0, stream>>>(i_deg, i_row, i_cur, N);
    k_scatter<<<(ET + 255) / 256, 256, 0, stream>>>(ei, E, N, i_cur, i_csr);

    // ---- layer 1 ----
    {
        dim3 grid(256 / 64, (N + 63) / 64);
        k_gemm1<<<grid, 256, 0, stream>>>(x, W1, h1b, N, 128, 256);
    }
    k_scores1<<<(N * 8 + 255) / 256, 256, 0, stream>>>(h1b, a1s, a1d, f_s1s, f_s1d, N * 8);
    k_wts1<<<nb4, 256, 0, stream>>>(f_s1s, f_s1d, i_row, i_csr, p1b, f_den1, N);
    k_agg1<<<nb4, 256, 0, stream>>>(h1b, p1b, f_den1, i_row, i_csr, b1, f_out1, N);

    // ---- layer 2 ----
    k_gemm2<<<(N + 31) / 32, 256, 0, stream>>>(f_out1, W2, a2s, a2d, h2b, f_s2s, f_s2d, N);
    k_wts2<<<nb4, 256, 0, stream>>>(f_s2s, f_s2d, i_row, i_csr, p2, f_den2, N);
    k_agg2<<<nb4, 256, 0, stream>>>(h2b, p2, f_den2, i_row, i_csr, b2, f_out2, N);

    // ---- log_softmax ----
    k_lsm<<<nb4, 256, 0, stream>>>(f_out2, out, N);
}

// Round 3
// 725.355 us; speedup vs baseline: 1.8205x; 1.3921x over previous
//
#include <hip/hip_runtime.h>
#include <hip/hip_bf16.h>
#include <cmath>

// ---------------------------------------------------------------------------
// GAT 2-layer forward.
//  - GEMMs via bf16 MFMA (16x16x32), single-stage LDS, fp32 accumulate.
//  - Edge softmax without max-subtraction (scores are O(1); exp never
//    overflows) -> one gather pass per layer for weights.
//  - k_agg1 split into 2 channel passes (128 ch each) for L2 locality.
//  - CSR via counting sort; parallel 3-phase scan.
//  - log_softmax fused into layer-2 aggregation.
// ---------------------------------------------------------------------------

#define LEAKY(e) ((e) >= 0.f ? (e) : 0.2f * (e))

typedef unsigned short ushortT;
typedef unsigned int uintT;
typedef __attribute__((ext_vector_type(8))) short short8;
typedef __attribute__((ext_vector_type(4))) float float4v;

static __device__ __forceinline__ float bf2f(ushortT u) {
    return __uint_as_float(((uintT)u) << 16);
}
static __device__ __forceinline__ float bflo(uintT u) {
    return __uint_as_float(u << 16);
}
static __device__ __forceinline__ float bfhi(uintT u) {
    return __uint_as_float(u & 0xffff0000u);
}
static __device__ __forceinline__ ushortT f2bf(float f) {
    __hip_bfloat16 h = __float2bfloat16(f);   // RNE
    return *reinterpret_cast<ushortT*>(&h);
}

// ---------------- GEMM1: x[M,128] @ W1[128,256] -> bf16 h1b[M,256] ---------
// block: 256 thr, tile 64 rows x 128 cols, K=128 single stage.
#define LDA1 136   // 128 + 8 pad (row = 272 B, 16B aligned, 2-way banks)
__global__ __launch_bounds__(256) void k_gemm1(const float* __restrict__ A,
                                               const float* __restrict__ B,
                                               ushortT* __restrict__ C, int M) {
    __shared__ ushortT As[64 * LDA1];
    __shared__ ushortT Bs[128 * LDA1];
    int tid = threadIdx.x;
    int r0 = blockIdx.y * 64;
    int c0 = blockIdx.x * 128;
    {   // stage A: rows r0..r0+63, k 0..127, fp32 -> bf16
        int row = tid >> 2;
        int kq = (tid & 3) * 32;
        int gr = r0 + row;
        #pragma unroll
        for (int i = 0; i < 8; ++i) {
            int k = kq + i * 4;
            float4 v = (gr < M) ? *(const float4*)(A + (size_t)gr * 128 + k)
                                : make_float4(0.f, 0.f, 0.f, 0.f);
            ushort4 u;
            u.x = f2bf(v.x); u.y = f2bf(v.y); u.z = f2bf(v.z); u.w = f2bf(v.w);
            *(ushort4*)(&As[row * LDA1 + k]) = u;
        }
    }
    {   // stage B: Bs[n][k] = W1[k][c0+n]  (transposed for MFMA B-frag reads)
        int k = tid >> 1;
        int h = (tid & 1) * 64;
        #pragma unroll
        for (int q = 0; q < 16; ++q) {
            int n = h + q * 4;
            float4 v = *(const float4*)(B + (size_t)k * 256 + c0 + n);
            Bs[(n + 0) * LDA1 + k] = f2bf(v.x);
            Bs[(n + 1) * LDA1 + k] = f2bf(v.y);
            Bs[(n + 2) * LDA1 + k] = f2bf(v.z);
            Bs[(n + 3) * LDA1 + k] = f2bf(v.w);
        }
    }
    __syncthreads();
    int lane = tid & 63, wave = tid >> 6;
    int m15 = lane & 15, quad = lane >> 4;
    int rw = wave * 16;
    float4v acc[8];
    #pragma unroll
    for (int j = 0; j < 8; ++j) acc[j] = (float4v){0.f, 0.f, 0.f, 0.f};
    #pragma unroll
    for (int s = 0; s < 4; ++s) {
        int k0 = s * 32 + quad * 8;
        short8 a = *(const short8*)(&As[(rw + m15) * LDA1 + k0]);
        #pragma unroll
        for (int j = 0; j < 8; ++j) {
            short8 b = *(const short8*)(&Bs[(j * 16 + m15) * LDA1 + k0]);
            acc[j] = __builtin_amdgcn_mfma_f32_16x16x32_bf16(a, b, acc[j], 0, 0, 0);
        }
    }
    #pragma unroll
    for (int j = 0; j < 8; ++j) {
        int col = c0 + j * 16 + m15;
        #pragma unroll
        for (int r = 0; r < 4; ++r) {
            int gr = r0 + rw + quad * 4 + r;
            if (gr < M) C[(size_t)gr * 256 + col] = f2bf(acc[j][r]);
        }
    }
}

// ---------------- scores layer 1: per (n, head) 32-dot over bf16 -----------
__global__ __launch_bounds__(256) void k_scores1(const ushortT* __restrict__ h1,
                                                 const float* __restrict__ a_s,
                                                 const float* __restrict__ a_d,
                                                 float* __restrict__ ss,
                                                 float* __restrict__ sd, int NH) {
    int t = blockIdx.x * blockDim.x + threadIdx.x;
    if (t >= NH) return;
    int h = t & 7;
    const uint4* row = (const uint4*)(h1 + (size_t)t * 32);
    const float* as = a_s + h * 32;
    const float* ad = a_d + h * 32;
    float s1 = 0.f, s2 = 0.f;
    #pragma unroll
    for (int q = 0; q < 4; ++q) {
        uint4 u = row[q];
        uintT w[4] = {u.x, u.y, u.z, u.w};
        #pragma unroll
        for (int k = 0; k < 4; ++k) {
            int c = q * 8 + k * 2;
            s1 += bflo(w[k]) * as[c] + bfhi(w[k]) * as[c + 1];
            s2 += bflo(w[k]) * ad[c] + bfhi(w[k]) * ad[c + 1];
        }
    }
    ss[t] = s1;
    sd[t] = s2;
}

// ---------------- CSR build ------------------------------------------------
__global__ __launch_bounds__(256) void k_deg(const int* __restrict__ ei, int E, int N,
                                             int* __restrict__ deg) {
    int e = blockIdx.x * blockDim.x + threadIdx.x;
    int total = E + N;
    if (e >= total) return;
    int dst = (e < E) ? ei[E + e] : (e - E);
    atomicAdd(&deg[dst], 1);
}

__global__ __launch_bounds__(1024) void k_scan_a(const int* __restrict__ deg,
                                                 int* __restrict__ tmp,
                                                 int* __restrict__ part, int n) {
    __shared__ int wsum[16];
    int t = threadIdx.x, lane = t & 63, wv = t >> 6;
    int i = blockIdx.x * 1024 + t;
    int v = (i < n) ? deg[i] : 0;
    int incl = v;
    #pragma unroll
    for (int off = 1; off < 64; off <<= 1) {
        int u = __shfl_up(incl, off, 64);
        if (lane >= off) incl += u;
    }
    if (lane == 63) wsum[wv] = incl;
    __syncthreads();
    if (wv == 0) {
        int s = (lane < 16) ? wsum[lane] : 0;
        #pragma unroll
        for (int off = 1; off < 16; off <<= 1) {
            int u = __shfl_up(s, off, 64);
            if (lane >= off) s += u;
        }
        if (lane < 16) wsum[lane] = s;
    }
    __syncthreads();
    int g = incl + (wv ? wsum[wv - 1] : 0);
    if (i < n) tmp[i] = g;
    if (t == 1023) part[blockIdx.x] = g;
}

__global__ __launch_bounds__(1024) void k_scan_b(int* __restrict__ part, int nb) {
    __shared__ int wsum[16];
    int t = threadIdx.x, lane = t & 63, wv = t >> 6;
    int v = (t < nb) ? part[t] : 0;
    int incl = v;
    #pragma unroll
    for (int off = 1; off < 64; off <<= 1) {
        int u = __shfl_up(incl, off, 64);
        if (lane >= off) incl += u;
    }
    if (lane == 63) wsum[wv] = incl;
    __syncthreads();
    if (wv == 0) {
        int s = (lane < 16) ? wsum[lane] : 0;
        #pragma unroll
        for (int off = 1; off < 16; off <<= 1) {
            int u = __shfl_up(s, off, 64);
            if (lane >= off) s += u;
        }
        if (lane < 16) wsum[lane] = s;
    }
    __syncthreads();
    int g = incl + (wv ? wsum[wv - 1] : 0);
    if (t < nb) part[t] = g;
}

__global__ __launch_bounds__(256) void k_scan_c(const int* __restrict__ deg,
                                                const int* __restrict__ tmp,
                                                const int* __restrict__ part,
                                                int* __restrict__ rowptr,
                                                int* __restrict__ cursor, int n) {
    int i = blockIdx.x * blockDim.x + threadIdx.x;
    if (i >= n) return;
    int b = i >> 10;
    int off = b ? part[b - 1] : 0;
    int incl = tmp[i] + off;
    rowptr[i + 1] = incl;
    cursor[i] = incl - deg[i];
    if (i == 0) rowptr[0] = 0;
}

__global__ __launch_bounds__(256) void k_scatter(const int* __restrict__ ei, int E, int N,
                                                 int* __restrict__ cursor,
                                                 int* __restrict__ csr_src) {
    int e = blockIdx.x * blockDim.x + threadIdx.x;
    int total = E + N;
    if (e >= total) return;
    int src, dst;
    if (e < E) { src = ei[e]; dst = ei[E + e]; }
    else       { src = dst = e - E; }
    int pos = atomicAdd(&cursor[dst], 1);
    csr_src[pos] = src;
}

// ---------------- layer-1 weights: wave per dst, 8 edges x 8 heads ---------
// No max subtraction: scores are O(+-5), exp is safe; alpha unchanged.
__global__ __launch_bounds__(256) void k_wts1(const float* __restrict__ ssrc,
                                              const float* __restrict__ sdst,
                                              const int* __restrict__ rowptr,
                                              const int* __restrict__ csr_src,
                                              ushortT* __restrict__ pbuf,
                                              float* __restrict__ denom, int N) {
    int lane = threadIdx.x & 63;
    int wid = threadIdx.x >> 6;
    int n = blockIdx.x * 4 + wid;
    if (n >= N) return;
    int head = lane & 7, es = lane >> 3;
    int beg = rowptr[n], end = rowptr[n + 1];
    float sdn = sdst[(size_t)n * 8 + head];
    float l = 0.f;
    for (int i0 = beg; i0 < end; i0 += 8) {
        int i = i0 + es;
        if (i < end) {
            int s = csr_src[i];
            float e = LEAKY(ssrc[(size_t)s * 8 + head] + sdn);
            ushortT pb = f2bf(__expf(e));
            pbuf[(size_t)i * 8 + head] = pb;
            l += bf2f(pb);
        }
    }
    l += __shfl_xor(l, 8, 64);
    l += __shfl_xor(l, 16, 64);
    l += __shfl_xor(l, 32, 64);
    if (es == 0) denom[(size_t)n * 8 + head] = l;
}

// ---------------- layer-1 aggregation: channel pass (128 ch), 2 edges/wave -
__global__ __launch_bounds__(256) void k_agg1(const ushortT* __restrict__ h1,
                                              const ushortT* __restrict__ pbuf,
                                              const float* __restrict__ denom,
                                              const int* __restrict__ rowptr,
                                              const int* __restrict__ csr_src,
                                              const float* __restrict__ b1,
                                              ushortT* __restrict__ out1,
                                              int N, int pass) {
    int lane = threadIdx.x & 63;
    int wid = threadIdx.x >> 6;
    int n = blockIdx.x * 4 + wid;
    if (n >= N) return;
    int half = lane >> 5, cl = lane & 31;   // half = edge parity, cl -> 4 ch
    int head = pass * 4 + (cl >> 3);
    int beg = rowptr[n], end = rowptr[n + 1];
    const ushortT* hbase = h1 + pass * 128 + cl * 4;
    float a0 = 0.f, a1 = 0.f, a2 = 0.f, a3 = 0.f;
    int idx = beg + half;
    uint2 vc = make_uint2(0u, 0u);
    float pc = 0.f;
    if (idx < end) {
        int s = csr_src[idx];
        pc = bf2f(pbuf[(size_t)idx * 8 + head]);
        vc = *(const uint2*)(hbase + (size_t)s * 256);
    }
    for (; idx < end; idx += 2) {
        uint2 vn = make_uint2(0u, 0u);
        float pn = 0.f;
        int idx2 = idx + 2;
        if (idx2 < end) {
            int s = csr_src[idx2];
            pn = bf2f(pbuf[(size_t)idx2 * 8 + head]);
            vn = *(const uint2*)(hbase + (size_t)s * 256);
        }
        a0 += pc * bflo(vc.x);
        a1 += pc * bfhi(vc.x);
        a2 += pc * bflo(vc.y);
        a3 += pc * bfhi(vc.y);
        vc = vn; pc = pn;
    }
    a0 += __shfl_xor(a0, 32, 64);
    a1 += __shfl_xor(a1, 32, 64);
    a2 += __shfl_xor(a2, 32, 64);
    a3 += __shfl_xor(a3, 32, 64);
    if (half == 0) {
        float inv = 1.f / denom[(size_t)n * 8 + head];
        const float4 bb = *(const float4*)(b1 + pass * 128 + cl * 4);
        ushort4 o;
        o.x = f2bf(fmaxf(a0 * inv + bb.x, 0.f));
        o.y = f2bf(fmaxf(a1 * inv + bb.y, 0.f));
        o.z = f2bf(fmaxf(a2 * inv + bb.z, 0.f));
        o.w = f2bf(fmaxf(a3 * inv + bb.w, 0.f));
        *(ushort4*)(out1 + (size_t)n * 256 + pass * 128 + cl * 4) = o;
    }
}

// ---------------- GEMM2: out1b[M,256] @ W2[256,40] -> bf16 h2b[M,40] -------
#define LDA2 264   // 256 + 8 pad
__global__ __launch_bounds__(256) void k_gemm2(const ushortT* __restrict__ X,
                                               const float* __restrict__ W,
                                               ushortT* __restrict__ H2, int M) {
    __shared__ ushortT As[64 * LDA2];
    __shared__ ushortT Bs[48 * LDA2];
    int tid = threadIdx.x;
    int r0 = blockIdx.x * 64;
    {   // stage A: 64 rows x 256 k bf16 (direct copy)
        int row = tid >> 2;
        int kq = (tid & 3) * 64;
        int gr = r0 + row;
        #pragma unroll
        for (int i = 0; i < 8; ++i) {
            int k = kq + i * 8;
            uint4 v = (gr < M) ? *(const uint4*)(X + (size_t)gr * 256 + k)
                               : make_uint4(0u, 0u, 0u, 0u);
            *(uint4*)(&As[row * LDA2 + k]) = v;
        }
    }
    {   // stage B: Bs[n][k] = W2[k][n], zero-pad n=40..47
        int k = tid;
        #pragma unroll
        for (int q = 0; q < 10; ++q) {
            float4 v = *(const float4*)(W + (size_t)k * 40 + q * 4);
            Bs[(q * 4 + 0) * LDA2 + k] = f2bf(v.x);
            Bs[(q * 4 + 1) * LDA2 + k] = f2bf(v.y);
            Bs[(q * 4 + 2) * LDA2 + k] = f2bf(v.z);
            Bs[(q * 4 + 3) * LDA2 + k] = f2bf(v.w);
        }
        #pragma unroll
        for (int n = 40; n < 48; ++n) Bs[n * LDA2 + k] = 0;
    }
    __syncthreads();
    int lane = tid & 63, wave = tid >> 6;
    int m15 = lane & 15, quad = lane >> 4;
    int rw = wave * 16;
    float4v acc[3];
    #pragma unroll
    for (int j = 0; j < 3; ++j) acc[j] = (float4v){0.f, 0.f, 0.f, 0.f};
    #pragma unroll
    for (int s = 0; s < 8; ++s) {
        int k0 = s * 32 + quad * 8;
        short8 a = *(const short8*)(&As[(rw + m15) * LDA2 + k0]);
        #pragma unroll
        for (int j = 0; j < 3; ++j) {
            short8 b = *(const short8*)(&Bs[(j * 16 + m15) * LDA2 + k0]);
            acc[j] = __builtin_amdgcn_mfma_f32_16x16x32_bf16(a, b, acc[j], 0, 0, 0);
        }
    }
    #pragma unroll
    for (int j = 0; j < 3; ++j) {
        int col = j * 16 + m15;
        if (col >= 40) continue;
        #pragma unroll
        for (int r = 0; r < 4; ++r) {
            int gr = r0 + rw + quad * 4 + r;
            if (gr < M) H2[(size_t)gr * 40 + col] = f2bf(acc[j][r]);
        }
    }
}

// ---------------- scores layer 2: per node 40-dot --------------------------
__global__ __launch_bounds__(256) void k_scores2(const ushortT* __restrict__ h2,
                                                 const float* __restrict__ a2s,
                                                 const float* __restrict__ a2d,
                                                 float* __restrict__ ss,
                                                 float* __restrict__ sd, int N) {
    int n = blockIdx.x * blockDim.x + threadIdx.x;
    if (n >= N) return;
    const uint4* row = (const uint4*)(h2 + (size_t)n * 40);
    float s1 = 0.f, s2 = 0.f;
    #pragma unroll
    for (int q = 0; q < 5; ++q) {
        uint4 u = row[q];
        uintT w[4] = {u.x, u.y, u.z, u.w};
        #pragma unroll
        for (int k = 0; k < 4; ++k) {
            int c = q * 8 + k * 2;
            s1 += bflo(w[k]) * a2s[c] + bfhi(w[k]) * a2s[c + 1];
            s2 += bflo(w[k]) * a2d[c] + bfhi(w[k]) * a2d[c + 1];
        }
    }
    ss[n] = s1;
    sd[n] = s2;
}

// ---------------- layer-2 weights: wave per dst (no max pass) --------------
__global__ __launch_bounds__(256) void k_wts2(const float* __restrict__ ss,
                                              const float* __restrict__ sd,
                                              const int* __restrict__ rowptr,
                                              const int* __restrict__ csr_src,
                                              float* __restrict__ pbuf,
                                              float* __restrict__ denom, int N) {
    int lane = threadIdx.x & 63;
    int wid = threadIdx.x >> 6;
    int n = blockIdx.x * 4 + wid;
    if (n >= N) return;
    int beg = rowptr[n], end = rowptr[n + 1];
    float sdn = sd[n];
    float l = 0.f;
    for (int i0 = beg; i0 < end; i0 += 64) {
        int i = i0 + lane;
        if (i < end) {
            float e = LEAKY(ss[csr_src[i]] + sdn);
            float p = __expf(e);
            pbuf[i] = p;
            l += p;
        }
    }
    #pragma unroll
    for (int off = 1; off < 64; off <<= 1) l += __shfl_xor(l, off, 64);
    if (lane == 0) denom[n] = l;
}

// ---------------- layer-2 aggregation + fused log_softmax ------------------
// wave per node; 6 edge-slots x 10 lanes (4 ch each) per iteration.
__global__ __launch_bounds__(256) void k_agg2lsm(const ushortT* __restrict__ h2,
                                                 const float* __restrict__ pbuf,
                                                 const float* __restrict__ denom,
                                                 const int* __restrict__ rowptr,
                                                 const int* __restrict__ csr_src,
                                                 const float* __restrict__ b2,
                                                 float* __restrict__ out, int N) {
    int lane = threadIdx.x & 63;
    int wid = threadIdx.x >> 6;
    int n = blockIdx.x * 4 + wid;
    if (n >= N) return;
    int el = lane / 10;
    int cl = lane - el * 10;
    bool act = (el < 6);
    int beg = rowptr[n], end = rowptr[n + 1];
    float a0 = 0.f, a1 = 0.f, a2 = 0.f, a3 = 0.f;
    if (act) {
        int idx = beg + el;
        uint2 vc = make_uint2(0u, 0u);
        float pc = 0.f;
        if (idx < end) {
            int s = csr_src[idx];
            pc = pbuf[idx];
            vc = *(const uint2*)(h2 + (size_t)s * 40 + cl * 4);
        }
        for (; idx < end; idx += 6) {
            uint2 vn = make_uint2(0u, 0u);
            float pn = 0.f;
            int idx2 = idx + 6;
            if (idx2 < end) {
                int s = csr_src[idx2];
                pn = pbuf[idx2];
                vn = *(const uint2*)(h2 + (size_t)s * 40 + cl * 4);
            }
            a0 += pc * bflo(vc.x);
            a1 += pc * bfhi(vc.x);
            a2 += pc * bflo(vc.y);
            a3 += pc * bfhi(vc.y);
            vc = vn; pc = pn;
        }
    }
    // gather the 6 slots into lanes 0..9
    float t0 = 0.f, t1 = 0.f, t2 = 0.f, t3 = 0.f;
    #pragma unroll
    for (int k = 0; k < 6; ++k) {
        int srcl = cl + 10 * k;
        t0 += __shfl(a0, srcl, 64);
        t1 += __shfl(a1, srcl, 64);
        t2 += __shfl(a2, srcl, 64);
        t3 += __shfl(a3, srcl, 64);
    }
    float inv = 1.f / denom[n];
    float o0 = t0 * inv + b2[cl * 4 + 0];
    float o1 = t1 * inv + b2[cl * 4 + 1];
    float o2 = t2 * inv + b2[cl * 4 + 2];
    float o3 = t3 * inv + b2[cl * 4 + 3];
    // fused log_softmax over the 40 values held by lanes 0..9
    float lm = (lane < 10) ? fmaxf(fmaxf(o0, o1), fmaxf(o2, o3)) : -INFINITY;
    #pragma unroll
    for (int off = 32; off; off >>= 1) lm = fmaxf(lm, __shfl_xor(lm, off, 64));
    float le = (lane < 10)
        ? __expf(o0 - lm) + __expf(o1 - lm) + __expf(o2 - lm) + __expf(o3 - lm)
        : 0.f;
    #pragma unroll
    for (int off = 32; off; off >>= 1) le += __shfl_xor(le, off, 64);
    float ls = lm + logf(le);
    if (lane < 10) {
        float4 w = make_float4(o0 - ls, o1 - ls, o2 - ls, o3 - ls);
        *(float4*)(out + (size_t)n * 40 + cl * 4) = w;
    }
}

// ---------------------------------------------------------------------------
extern "C" void kernel_launch(void* const* d_in, const int* in_sizes, int n_in,
                              void* d_out, int out_size, void* d_ws, size_t ws_size,
                              hipStream_t stream) {
    const float* x   = (const float*)d_in[0];
    const int*   ei  = (const int*)d_in[1];
    const float* W1  = (const float*)d_in[2];
    const float* a1s = (const float*)d_in[3];
    const float* a1d = (const float*)d_in[4];
    const float* b1  = (const float*)d_in[5];
    const float* W2  = (const float*)d_in[6];
    const float* a2s = (const float*)d_in[7];
    const float* a2d = (const float*)d_in[8];
    const float* b2  = (const float*)d_in[9];
    float* out = (float*)d_out;

    const int N = in_sizes[0] / 128;   // 100000
    const int E = in_sizes[1] / 2;     // 1600000
    const int ET = E + N;

    // ---- workspace layout ----
    char* w = (char*)d_ws;
    ushortT* h1b   = (ushortT*)w;                         // N*256 bf16
    ushortT* out1b = h1b + (size_t)N * 256;               // N*256 bf16
    float* s1s  = (float*)(out1b + (size_t)N * 256);      // N*8
    float* s1d  = s1s + (size_t)N * 8;
    float* den1 = s1d + (size_t)N * 8;
    ushortT* p1b = (ushortT*)(den1 + (size_t)N * 8);      // ET*8 bf16
    int* i_deg = (int*)(p1b + (size_t)ET * 8);
    int* i_row = i_deg + (N + 16);
    int* i_cur = i_row + (N + 16);
    int* i_tmp = i_cur + (N + 16);
    int* i_par = i_tmp + (N + 16);
    int* i_csr = i_par + 2048;                            // ET ints
    // layer-2 buffers overlay h1b (dead after k_agg1 pass 1)
    ushortT* h2b = (ushortT*)w;                           // N*40 bf16
    float* p2   = (float*)(w + (size_t)N * 40 * 2);       // ET f32
    float* s2s  = p2 + ET;
    float* s2d  = s2s + N;
    float* den2 = s2d + N;

    const int nb4 = (N + 3) / 4;
    const int nbs = (N + 1023) / 1024;

    // ---- CSR build ----
    hipMemsetAsync(i_deg, 0, (size_t)N * sizeof(int), stream);
    k_deg<<<(ET + 255) / 256, 256, 0, stream>>>(ei, E, N, i_deg);
    k_scan_a<<<nbs, 1024, 0, stream>>>(i_deg, i_tmp, i_par, N);
    k_scan_b<<<1, 1024, 0, stream>>>(i_par, nbs);
    k_scan_c<<<(N + 255) / 256, 256, 0, stream>>>(i_deg, i_tmp, i_par, i_row, i_cur, N);
    k_scatter<<<(ET + 255) / 256, 256, 0, stream>>>(ei, E, N, i_cur, i_csr);

    // ---- layer 1 ----
    {
        dim3 grid(2, (N + 63) / 64);
        k_gemm1<<<grid, 256, 0, stream>>>(x, W1, h1b, N);
    }
    k_scores1<<<(N * 8 + 255) / 256, 256, 0, stream>>>(h1b, a1s, a1d, s1s, s1d, N * 8);
    k_wts1<<<nb4, 256, 0, stream>>>(s1s, s1d, i_row, i_csr, p1b, den1, N);
    k_agg1<<<nb4, 256, 0, stream>>>(h1b, p1b, den1, i_row, i_csr, b1, out1b, N, 0);
    k_agg1<<<nb4, 256, 0, stream>>>(h1b, p1b, den1, i_row, i_csr, b1, out1b, N, 1);

    // ---- layer 2 ----
    k_gemm2<<<(N + 63) / 64, 256, 0, stream>>>(out1b, W2, h2b, N);
    k_scores2<<<(N + 255) / 256, 256, 0, stream>>>(h2b, a2s, a2d, s2s, s2d, N);
    k_wts2<<<nb4, 256, 0, stream>>>(s2s, s2d, i_row, i_csr, p2, den2, N);
    k_agg2lsm<<<nb4, 256, 0, stream>>>(h2b, p2, den2, i_row, i_csr, b2, out, N);
}